// Round 8
// baseline (108.790 us; speedup 1.0000x reference)
//
#include <hip/hip_runtime.h>
#include <math.h>

// WaveletLayer: (B=4096, S=50, H=256) fp32.
// Per (b,h): 3-level db3 wavedec (ptwt reflect) -> per-band filter multiply ->
// waverec -> +residual -> LayerNorm over H.
// Round-7 = round-6 restructure with the cvt_pkrtz type fix:
//  (a) No phase-0 staging: thread h loads its own column via 50 coalesced
//      strided dwords + v_cvt_pkrtz -> pipeline. One barrier total.
//  (b) y slab is row-major f16 [50][256]; LN phase assigns one full row per
//      32-lane half-wave (f16x8/lane): 5-level butterfly, 2 chains ->
//      10 shuffles per 2 rows instead of 24.
//  (c) fp16x2-packed wavelet pipeline unchanged (passed at absmax 0.031).

#define S_LEN 50
#define H_DIM 256
#define NPAIR 25

typedef _Float16 f16;
typedef __attribute__((ext_vector_type(2))) _Float16 f16x2;
typedef __attribute__((ext_vector_type(8))) _Float16 f16x8;

// d_ws layout (f16x2 elements): ft01 [10][256] | ft2 [8][256] | ft3 [14][256]
#define FT01_OFF 0
#define FT2_OFF (10 * H_DIM)
#define FT3_OFF (18 * H_DIM)
#define FT_BYTES (32 * H_DIM * 4)  // 32768

__device__ constexpr float DLO[6] = {
    0.035226291882100656f, -0.08544127388224149f, -0.13501102001039084f,
    0.4598775021193313f,   0.8068915093133388f,   0.3326705529509569f};
__device__ constexpr float DHI[6] = {
    -0.3326705529509569f,  0.8068915093133388f,  -0.4598775021193313f,
    -0.13501102001039084f, 0.08544127388224149f,  0.035226291882100656f};

static __device__ __forceinline__ f16x2 splat2(f16 v) {
  f16x2 r; r.x = v; r.y = v; return r;
}
static __device__ __forceinline__ f16x2 mk2(float a, float b) {
  f16x2 r; r.x = (f16)a; r.y = (f16)b; return r;
}
static __device__ __forceinline__ f16x2 pk2(float a, float b) {
  return __builtin_bit_cast(f16x2, __builtin_amdgcn_cvt_pkrtz(a, b));
}

// Transpose+pack the learned filters into [l][h]-major f16x2 in ws.
__global__ void prep_filters(const float* __restrict__ f0,
                             const float* __restrict__ f1,
                             const float* __restrict__ f2,
                             const float* __restrict__ f3,
                             f16x2* __restrict__ ft) {
  const int h = threadIdx.x;
  const int b = blockIdx.x;
  if (b < 10) {  // (f0, f1) pair at tap l
    const int l = b;
    f16x2 v; v.x = (f16)f0[h * 10 + l]; v.y = (f16)f1[h * 10 + l];
    ft[FT01_OFF + l * H_DIM + h] = v;
  } else if (b < 18) {  // f2 taps (2k, 2k+1)
    const int k = b - 10;
    f16x2 v; v.x = (f16)f2[h * 16 + 2 * k]; v.y = (f16)f2[h * 16 + 2 * k + 1];
    ft[FT2_OFF + k * H_DIM + h] = v;
  } else {  // f3 taps (2k, 2k+1), last pair padded
    const int k = b - 18;
    f16x2 v;
    v.x = (f16)f3[h * 27 + 2 * k];
    v.y = (2 * k + 1 < 27) ? (f16)f3[h * 27 + 2 * k + 1] : (f16)0.f;
    ft[FT3_OFF + k * H_DIM + h] = v;
  }
}

// One analysis level, (lo,hi)-packed. out[i] = {cA[i], cD[i]}.
template <int N, class Get>
__device__ __forceinline__ void dwt_f16(const Get& X, f16x2* out) {
  constexpr int M = (N + 5) / 2;
#pragma unroll
  for (int i = 0; i < M; ++i) {
    f16x2 acc = mk2(0.f, 0.f);
#pragma unroll
    for (int j = 0; j < 6; ++j) {
      int idx = 2 * i + j - 4;
      idx = idx < 0 ? -idx : idx;
      idx = idx >= N ? 2 * N - 2 - idx : idx;
      acc += splat2(X(idx)) * mk2(DLO[5 - j], DHI[5 - j]);
    }
    out[i] = acc;
  }
}

// One synthesis level, adjacent-packed output: out2[t] = {rec[2t], rec[2t+1]}.
template <int T, class GLo, class GHi>
__device__ __forceinline__ void idwt_f16(const GLo& lo, const GHi& hi,
                                         f16x2* out2) {
#pragma unroll
  for (int t = 0; t < T / 2; ++t) {
    f16x2 acc = mk2(0.f, 0.f);
#pragma unroll
    for (int k = 0; k < 3; ++k) {
      acc += splat2(lo(t + k)) * mk2(DLO[2 * k + 1], DLO[2 * k]);
      acc += splat2(hi(t + k)) * mk2(DHI[2 * k + 1], DHI[2 * k]);
    }
    out2[t] = acc;
  }
  if constexpr (T & 1) {  // tail p = T-1 (even): taps {1,3,5}
    constexpr int t0 = T / 2;
    f16 s = (f16)0.f;
#pragma unroll
    for (int k = 0; k < 3; ++k)
      s += lo(t0 + k) * (f16)DLO[2 * k + 1] + hi(t0 + k) * (f16)DHI[2 * k + 1];
    f16x2 r; r.x = s; r.y = (f16)0.f;
    out2[t0] = r;
  }
}

template <bool USE_WS>
__global__ __launch_bounds__(256)
__attribute__((amdgpu_waves_per_eu(5, 8)))
void wavelet_ln_kernel(
    const float* __restrict__ in, const float* __restrict__ f0,
    const float* __restrict__ f1, const float* __restrict__ f2,
    const float* __restrict__ f3, const f16x2* __restrict__ ft,
    const float* __restrict__ gam, const float* __restrict__ bet,
    float* __restrict__ out) {
  __shared__ f16 slab[S_LEN][H_DIM];  // row-major y, 25600 B -> 6 blocks/CU
  const int tid = threadIdx.x;
  const size_t base = (size_t)blockIdx.x * (S_LEN * H_DIM);
  const float* __restrict__ inp = in + base;

  const int h = tid;

  // ---- phase A: direct column loads + packed fp16 wavelet pipeline ----
  {
    f16x2 xp[NPAIR];
#pragma unroll
    for (int t = 0; t < NPAIR; ++t) {
      const float a = inp[(2 * t) * H_DIM + h];      // coalesced 256B/wave
      const float b = inp[(2 * t + 1) * H_DIM + h];  // coalesced 256B/wave
      xp[t] = pk2(a, b);                             // 1 instr per pair
    }

    f16x2 AD1[27];
    dwt_f16<50>([&](int s) -> f16 { return (s & 1) ? xp[s >> 1].y
                                                   : xp[s >> 1].x; }, AD1);
    f16x2 AD2[16];
    dwt_f16<27>([&](int s) -> f16 { return AD1[s].x; }, AD2);
    f16x2 AD3[10];
    dwt_f16<16>([&](int s) -> f16 { return AD2[s].x; }, AD3);

    // per-band learned filter multiply
    if constexpr (USE_WS) {
      // coalesced [l][h]-major packed loads (4 lines/wave-instr)
#pragma unroll
      for (int l = 0; l < 10; ++l) AD3[l] *= ft[FT01_OFF + l * H_DIM + h];
#pragma unroll
      for (int k = 0; k < 8; ++k) {
        const f16x2 c = ft[FT2_OFF + k * H_DIM + h];
        AD2[2 * k].y *= c.x;
        AD2[2 * k + 1].y *= c.y;
      }
#pragma unroll
      for (int k = 0; k < 14; ++k) {
        const f16x2 c = ft[FT3_OFF + k * H_DIM + h];
        AD1[2 * k].y *= c.x;
        if (2 * k + 1 < 27) AD1[2 * k + 1].y *= c.y;
      }
    } else {  // fallback: direct (gathered) loads
      const float* f0h = f0 + h * 10;
      const float* f1h = f1 + h * 10;
#pragma unroll
      for (int l = 0; l < 10; ++l) AD3[l] *= mk2(f0h[l], f1h[l]);
      const float* f2h = f2 + h * 16;
#pragma unroll
      for (int l = 0; l < 16; ++l) AD2[l].y *= (f16)f2h[l];
      const float* f3h = f3 + h * 27;
#pragma unroll
      for (int l = 0; l < 27; ++l) AD1[l].y *= (f16)f3h[l];
    }

    // synthesis
    f16x2 rr2[8];
    idwt_f16<16>([&](int s) -> f16 { return AD3[s].x; },
                 [&](int s) -> f16 { return AD3[s].y; }, rr2);
    f16x2 rr1[14];
    idwt_f16<27>([&](int s) -> f16 { return (s & 1) ? rr2[s >> 1].y
                                                    : rr2[s >> 1].x; },
                 [&](int s) -> f16 { return AD2[s].y; }, rr1);

    // final level fused with residual: slab <- y = x + rec, row-major
    auto lo = [&](int s) -> f16 { return (s & 1) ? rr1[s >> 1].y
                                                 : rr1[s >> 1].x; };
    auto hi = [&](int s) -> f16 { return AD1[s].y; };
#pragma unroll
    for (int t = 0; t < NPAIR; ++t) {
      f16x2 acc = mk2(0.f, 0.f);
#pragma unroll
      for (int k = 0; k < 3; ++k) {
        acc += splat2(lo(t + k)) * mk2(DLO[2 * k + 1], DLO[2 * k]);
        acc += splat2(hi(t + k)) * mk2(DHI[2 * k + 1], DHI[2 * k]);
      }
      const f16x2 y = xp[t] + acc;
      slab[2 * t][h] = y.x;      // 2B/lane consecutive -> 2-way, free
      slab[2 * t + 1][h] = y.y;
    }
  }
  __syncthreads();

  // ---- phase B: LN over H; one full row per 32-lane half-wave ----
  const int lane = tid & 63;
  const int wv = tid >> 6;
  const int half = lane >> 5;   // 0: even row of pair, 1: odd row
  const int hq = lane & 31;     // owns h = 8*hq .. 8*hq+7
  const float4 ga = ((const float4*)gam)[2 * hq];
  const float4 gb = ((const float4*)gam)[2 * hq + 1];
  const float4 ba = ((const float4*)bet)[2 * hq];
  const float4 bb = ((const float4*)bet)[2 * hq + 1];
  float* __restrict__ outp = out + base;
  for (int p = wv; p < NPAIR; p += 4) {
    const int row = 2 * p + half;
    const f16x8 v8 = *(const f16x8*)&slab[row][hq * 8];
    const float y0 = (float)v8.s0, y1 = (float)v8.s1;
    const float y2 = (float)v8.s2, y3 = (float)v8.s3;
    const float y4 = (float)v8.s4, y5 = (float)v8.s5;
    const float y6 = (float)v8.s6, y7 = (float)v8.s7;
    float sum = ((y0 + y1) + (y2 + y3)) + ((y4 + y5) + (y6 + y7));
    float ssq = y0 * y0 + y1 * y1 + y2 * y2 + y3 * y3 +
                y4 * y4 + y5 * y5 + y6 * y6 + y7 * y7;
#pragma unroll
    for (int o = 16; o >= 1; o >>= 1) {  // 5 levels, stays within half-wave
      sum += __shfl_xor(sum, o);
      ssq += __shfl_xor(ssq, o);
    }
    const float mu = sum * (1.0f / H_DIM);
    const float var = fmaxf(ssq * (1.0f / H_DIM) - mu * mu, 0.0f);
    const float rs = rsqrtf(var + 1e-12f);
    float4 o1, o2;
    o1.x = (y0 - mu) * rs * ga.x + ba.x;
    o1.y = (y1 - mu) * rs * ga.y + ba.y;
    o1.z = (y2 - mu) * rs * ga.z + ba.z;
    o1.w = (y3 - mu) * rs * ga.w + ba.w;
    o2.x = (y4 - mu) * rs * gb.x + bb.x;
    o2.y = (y5 - mu) * rs * gb.y + bb.y;
    o2.z = (y6 - mu) * rs * gb.z + bb.z;
    o2.w = (y7 - mu) * rs * gb.w + bb.w;
    float4* dst = (float4*)&outp[row * H_DIM + hq * 8];
    dst[0] = o1;  // half-wave covers the full 1KB row
    dst[1] = o2;
  }
}

extern "C" void kernel_launch(void* const* d_in, const int* in_sizes, int n_in,
                              void* d_out, int out_size, void* d_ws,
                              size_t ws_size, hipStream_t stream) {
  // setup_inputs() dict order: input_tensor, ln_gamma, ln_beta, filt0..filt3
  const float* in = (const float*)d_in[0];
  const float* gam = (const float*)d_in[1];
  const float* bet = (const float*)d_in[2];
  const float* f0 = (const float*)d_in[3];
  const float* f1 = (const float*)d_in[4];
  const float* f2 = (const float*)d_in[5];
  const float* f3 = (const float*)d_in[6];
  float* out = (float*)d_out;

  if (ws_size >= (size_t)FT_BYTES) {
    f16x2* ft = (f16x2*)d_ws;
    prep_filters<<<32, 256, 0, stream>>>(f0, f1, f2, f3, ft);
    wavelet_ln_kernel<true><<<4096, 256, 0, stream>>>(in, f0, f1, f2, f3, ft,
                                                      gam, bet, out);
  } else {
    wavelet_ln_kernel<false><<<4096, 256, 0, stream>>>(
        in, f0, f1, f2, f3, nullptr, gam, bet, out);
  }
}

// Round 9
// 101.151 us; speedup vs baseline: 1.0755x; 1.0755x over previous
//
#include <hip/hip_runtime.h>
#include <math.h>

// WaveletLayer: (B=4096, S=50, H=256) fp32.
// Per (b,h): 3-level db3 wavedec (ptwt reflect) -> per-band filter multiply ->
// waverec -> +residual -> LayerNorm over H.
// Round-8 = r5's spill-free staged load path + r7's cheap row-major LN:
//  phase 0: float4 global -> f16x2 pair-layout LDS (latency-decoupled staging;
//           r7 proved direct strided loads cause 32B/thread scratch spills).
//  phase A: 25 ds_read_b32 -> packed fp16 pipeline in regs (barrier after
//           reads: slab is re-written row-major below).
//  phase A': slab <- y = x + rec as row-major f16 [50][256].
//  phase B: one full row per 32-lane half-wave; 5-level butterfly (10
//           shuffles / 2 rows); dense 512B store instructions.

#define S_LEN 50
#define H_DIM 256
#define NPAIR 25

typedef _Float16 f16;
typedef __attribute__((ext_vector_type(2))) _Float16 f16x2;
typedef __attribute__((ext_vector_type(4))) _Float16 f16x4;
typedef __attribute__((ext_vector_type(8))) _Float16 f16x8;

// d_ws layout (f16x2 elements): ft01 [10][256] | ft2 [8][256] | ft3 [14][256]
#define FT01_OFF 0
#define FT2_OFF (10 * H_DIM)
#define FT3_OFF (18 * H_DIM)
#define FT_BYTES (32 * H_DIM * 4)  // 32768

__device__ constexpr float DLO[6] = {
    0.035226291882100656f, -0.08544127388224149f, -0.13501102001039084f,
    0.4598775021193313f,   0.8068915093133388f,   0.3326705529509569f};
__device__ constexpr float DHI[6] = {
    -0.3326705529509569f,  0.8068915093133388f,  -0.4598775021193313f,
    -0.13501102001039084f, 0.08544127388224149f,  0.035226291882100656f};

static __device__ __forceinline__ f16x2 splat2(f16 v) {
  f16x2 r; r.x = v; r.y = v; return r;
}
static __device__ __forceinline__ f16x2 mk2(float a, float b) {
  f16x2 r; r.x = (f16)a; r.y = (f16)b; return r;
}

// Transpose+pack the learned filters into [l][h]-major f16x2 in ws.
__global__ void prep_filters(const float* __restrict__ f0,
                             const float* __restrict__ f1,
                             const float* __restrict__ f2,
                             const float* __restrict__ f3,
                             f16x2* __restrict__ ft) {
  const int h = threadIdx.x;
  const int b = blockIdx.x;
  if (b < 10) {  // (f0, f1) pair at tap l
    const int l = b;
    f16x2 v; v.x = (f16)f0[h * 10 + l]; v.y = (f16)f1[h * 10 + l];
    ft[FT01_OFF + l * H_DIM + h] = v;
  } else if (b < 18) {  // f2 taps (2k, 2k+1)
    const int k = b - 10;
    f16x2 v; v.x = (f16)f2[h * 16 + 2 * k]; v.y = (f16)f2[h * 16 + 2 * k + 1];
    ft[FT2_OFF + k * H_DIM + h] = v;
  } else {  // f3 taps (2k, 2k+1), last pair padded
    const int k = b - 18;
    f16x2 v;
    v.x = (f16)f3[h * 27 + 2 * k];
    v.y = (2 * k + 1 < 27) ? (f16)f3[h * 27 + 2 * k + 1] : (f16)0.f;
    ft[FT3_OFF + k * H_DIM + h] = v;
  }
}

// One analysis level, (lo,hi)-packed. out[i] = {cA[i], cD[i]}.
template <int N, class Get>
__device__ __forceinline__ void dwt_f16(const Get& X, f16x2* out) {
  constexpr int M = (N + 5) / 2;
#pragma unroll
  for (int i = 0; i < M; ++i) {
    f16x2 acc = mk2(0.f, 0.f);
#pragma unroll
    for (int j = 0; j < 6; ++j) {
      int idx = 2 * i + j - 4;
      idx = idx < 0 ? -idx : idx;
      idx = idx >= N ? 2 * N - 2 - idx : idx;
      acc += splat2(X(idx)) * mk2(DLO[5 - j], DHI[5 - j]);
    }
    out[i] = acc;
  }
}

// One synthesis level, adjacent-packed output: out2[t] = {rec[2t], rec[2t+1]}.
template <int T, class GLo, class GHi>
__device__ __forceinline__ void idwt_f16(const GLo& lo, const GHi& hi,
                                         f16x2* out2) {
#pragma unroll
  for (int t = 0; t < T / 2; ++t) {
    f16x2 acc = mk2(0.f, 0.f);
#pragma unroll
    for (int k = 0; k < 3; ++k) {
      acc += splat2(lo(t + k)) * mk2(DLO[2 * k + 1], DLO[2 * k]);
      acc += splat2(hi(t + k)) * mk2(DHI[2 * k + 1], DHI[2 * k]);
    }
    out2[t] = acc;
  }
  if constexpr (T & 1) {  // tail p = T-1 (even): taps {1,3,5}
    constexpr int t0 = T / 2;
    f16 s = (f16)0.f;
#pragma unroll
    for (int k = 0; k < 3; ++k)
      s += lo(t0 + k) * (f16)DLO[2 * k + 1] + hi(t0 + k) * (f16)DHI[2 * k + 1];
    f16x2 r; r.x = s; r.y = (f16)0.f;
    out2[t0] = r;
  }
}

template <bool USE_WS>
__global__ __launch_bounds__(256)
__attribute__((amdgpu_waves_per_eu(5, 8)))
void wavelet_ln_kernel(
    const float* __restrict__ in, const float* __restrict__ f0,
    const float* __restrict__ f1, const float* __restrict__ f2,
    const float* __restrict__ f3, const f16x2* __restrict__ ft,
    const float* __restrict__ gam, const float* __restrict__ bet,
    float* __restrict__ out) {
  __shared__ f16 slab[S_LEN * H_DIM];  // 25600 B -> up to 6 blocks/CU
  const int tid = threadIdx.x;
  const size_t base = (size_t)blockIdx.x * (S_LEN * H_DIM);
  const float4* in4 = (const float4*)(in + base);

  // ---- phase 0: stage x as f16 pairs {x[2t],x[2t+1]} per h (float4 loads) --
  {
    f16x8* s8 = (f16x8*)slab;
#pragma unroll
    for (int i = 0; i < 7; ++i) {
      const int idx = i * 256 + tid;  // quad-of-pairs index in [0,1600)
      if (idx < NPAIR * 64) {
        const int t = idx >> 6, hq = idx & 63;
        const float4 a = in4[(2 * t) * 64 + hq];
        const float4 b = in4[(2 * t + 1) * 64 + hq];
        f16x8 o;
        o.s0 = (f16)a.x; o.s1 = (f16)b.x;
        o.s2 = (f16)a.y; o.s3 = (f16)b.y;
        o.s4 = (f16)a.z; o.s5 = (f16)b.z;
        o.s6 = (f16)a.w; o.s7 = (f16)b.w;
        s8[idx] = o;
      }
    }
  }
  __syncthreads();

  const int h = tid;

  // ---- phase A: pair reads -> packed fp16 wavelet pipeline in registers ----
  {
    f16x2 xp[NPAIR];
    const f16x2* sp = (const f16x2*)slab;
#pragma unroll
    for (int t = 0; t < NPAIR; ++t) xp[t] = sp[t * H_DIM + h];  // 2-way, free
    __syncthreads();  // slab gets re-written row-major below

    f16x2 AD1[27];
    dwt_f16<50>([&](int s) -> f16 { return (s & 1) ? xp[s >> 1].y
                                                   : xp[s >> 1].x; }, AD1);
    f16x2 AD2[16];
    dwt_f16<27>([&](int s) -> f16 { return AD1[s].x; }, AD2);
    f16x2 AD3[10];
    dwt_f16<16>([&](int s) -> f16 { return AD2[s].x; }, AD3);

    // per-band learned filter multiply
    if constexpr (USE_WS) {
      // coalesced [l][h]-major packed loads (4 lines/wave-instr)
#pragma unroll
      for (int l = 0; l < 10; ++l) AD3[l] *= ft[FT01_OFF + l * H_DIM + h];
#pragma unroll
      for (int k = 0; k < 8; ++k) {
        const f16x2 c = ft[FT2_OFF + k * H_DIM + h];
        AD2[2 * k].y *= c.x;
        AD2[2 * k + 1].y *= c.y;
      }
#pragma unroll
      for (int k = 0; k < 14; ++k) {
        const f16x2 c = ft[FT3_OFF + k * H_DIM + h];
        AD1[2 * k].y *= c.x;
        if (2 * k + 1 < 27) AD1[2 * k + 1].y *= c.y;
      }
    } else {  // fallback: direct (gathered) loads
      const float* f0h = f0 + h * 10;
      const float* f1h = f1 + h * 10;
#pragma unroll
      for (int l = 0; l < 10; ++l) AD3[l] *= mk2(f0h[l], f1h[l]);
      const float* f2h = f2 + h * 16;
#pragma unroll
      for (int l = 0; l < 16; ++l) AD2[l].y *= (f16)f2h[l];
      const float* f3h = f3 + h * 27;
#pragma unroll
      for (int l = 0; l < 27; ++l) AD1[l].y *= (f16)f3h[l];
    }

    // synthesis
    f16x2 rr2[8];
    idwt_f16<16>([&](int s) -> f16 { return AD3[s].x; },
                 [&](int s) -> f16 { return AD3[s].y; }, rr2);
    f16x2 rr1[14];
    idwt_f16<27>([&](int s) -> f16 { return (s & 1) ? rr2[s >> 1].y
                                                    : rr2[s >> 1].x; },
                 [&](int s) -> f16 { return AD2[s].y; }, rr1);

    // final level fused with residual: slab <- y = x + rec, ROW-MAJOR
    auto lo = [&](int s) -> f16 { return (s & 1) ? rr1[s >> 1].y
                                                 : rr1[s >> 1].x; };
    auto hi = [&](int s) -> f16 { return AD1[s].y; };
#pragma unroll
    for (int t = 0; t < NPAIR; ++t) {
      f16x2 acc = mk2(0.f, 0.f);
#pragma unroll
      for (int k = 0; k < 3; ++k) {
        acc += splat2(lo(t + k)) * mk2(DLO[2 * k + 1], DLO[2 * k]);
        acc += splat2(hi(t + k)) * mk2(DHI[2 * k + 1], DHI[2 * k]);
      }
      const f16x2 y = xp[t] + acc;
      slab[(2 * t) * H_DIM + h] = y.x;      // 2B/lane consecutive, 2-way free
      slab[(2 * t + 1) * H_DIM + h] = y.y;
    }
  }
  __syncthreads();

  // ---- phase B: LN over H; one full row per 32-lane half-wave ----
  const int lane = tid & 63;
  const int wv = tid >> 6;
  const int half = lane >> 5;   // row parity within the pair
  const int hq = lane & 31;     // owns h = 4hq..4hq+3 and 128+4hq..128+4hq+3
  const float4 ga = ((const float4*)gam)[hq];
  const float4 gb = ((const float4*)gam)[hq + 32];
  const float4 ba = ((const float4*)bet)[hq];
  const float4 bb = ((const float4*)bet)[hq + 32];
  float* __restrict__ outp = out + base;
  for (int p = wv; p < NPAIR; p += 4) {
    const int row = 2 * p + half;
    const f16x4 va = *(const f16x4*)&slab[row * H_DIM + hq * 4];
    const f16x4 vb = *(const f16x4*)&slab[row * H_DIM + 128 + hq * 4];
    const float y0 = (float)va.x, y1 = (float)va.y;
    const float y2 = (float)va.z, y3 = (float)va.w;
    const float y4 = (float)vb.x, y5 = (float)vb.y;
    const float y6 = (float)vb.z, y7 = (float)vb.w;
    float sum = ((y0 + y1) + (y2 + y3)) + ((y4 + y5) + (y6 + y7));
    float ssq = y0 * y0 + y1 * y1 + y2 * y2 + y3 * y3 +
                y4 * y4 + y5 * y5 + y6 * y6 + y7 * y7;
#pragma unroll
    for (int o = 16; o >= 1; o >>= 1) {  // 5 levels, stays within half-wave
      sum += __shfl_xor(sum, o);
      ssq += __shfl_xor(ssq, o);
    }
    const float mu = sum * (1.0f / H_DIM);
    const float var = fmaxf(ssq * (1.0f / H_DIM) - mu * mu, 0.0f);
    const float rs = rsqrtf(var + 1e-12f);
    float4 o1, o2;
    o1.x = (y0 - mu) * rs * ga.x + ba.x;
    o1.y = (y1 - mu) * rs * ga.y + ba.y;
    o1.z = (y2 - mu) * rs * ga.z + ba.z;
    o1.w = (y3 - mu) * rs * ga.w + ba.w;
    o2.x = (y4 - mu) * rs * gb.x + bb.x;
    o2.y = (y5 - mu) * rs * gb.y + bb.y;
    o2.z = (y6 - mu) * rs * gb.z + bb.z;
    o2.w = (y7 - mu) * rs * gb.w + bb.w;
    float4* row4 = (float4*)(outp + row * H_DIM);
    row4[hq] = o1;        // dense 512B per store instruction
    row4[hq + 32] = o2;
  }
}

extern "C" void kernel_launch(void* const* d_in, const int* in_sizes, int n_in,
                              void* d_out, int out_size, void* d_ws,
                              size_t ws_size, hipStream_t stream) {
  // setup_inputs() dict order: input_tensor, ln_gamma, ln_beta, filt0..filt3
  const float* in = (const float*)d_in[0];
  const float* gam = (const float*)d_in[1];
  const float* bet = (const float*)d_in[2];
  const float* f0 = (const float*)d_in[3];
  const float* f1 = (const float*)d_in[4];
  const float* f2 = (const float*)d_in[5];
  const float* f3 = (const float*)d_in[6];
  float* out = (float*)d_out;

  if (ws_size >= (size_t)FT_BYTES) {
    f16x2* ft = (f16x2*)d_ws;
    prep_filters<<<32, 256, 0, stream>>>(f0, f1, f2, f3, ft);
    wavelet_ln_kernel<true><<<4096, 256, 0, stream>>>(in, f0, f1, f2, f3, ft,
                                                      gam, bet, out);
  } else {
    wavelet_ln_kernel<false><<<4096, 256, 0, stream>>>(
        in, f0, f1, f2, f3, nullptr, gam, bet, out);
  }
}